// Round 1
// baseline (1778.333 us; speedup 1.0000x reference)
//
#include <hip/hip_runtime.h>
#include <math.h>

#define D 64
#define NUM_USERS 100000
#define NUM_ITEMS 50000
#define N_NODES 150000   // NUM_USERS + NUM_ITEMS
#define NNZ 2400000
#define BATCH 8192
#define NEG_SLOPE 0.1f
#define EPS_NRM 1e-12f

__device__ __forceinline__ float wave_sum64(float v) {
    // butterfly reduction across the 64-lane wave
    #pragma unroll
    for (int off = 32; off > 0; off >>= 1)
        v += __shfl_xor(v, off, 64);
    return v;
}

// pref = lrelu_l2norm(concat(user_pref, item_pref)); acc = pref; p = pref
__global__ void init_kernel(const float* __restrict__ upref,
                            const float* __restrict__ ipref,
                            float* __restrict__ acc,
                            float* __restrict__ p) {
    int row  = blockIdx.x * 4 + (threadIdx.x >> 6);
    int lane = threadIdx.x & 63;
    if (row >= N_NODES) return;
    float x = (row < NUM_USERS) ? upref[(size_t)row * D + lane]
                                : ipref[(size_t)(row - NUM_USERS) * D + lane];
    x = (x >= 0.f) ? x : NEG_SLOPE * x;
    float norm = sqrtf(wave_sum64(x * x));
    float y = x / fmaxf(norm, EPS_NRM);
    size_t idx = (size_t)row * D + lane;
    acc[idx] = y;
    p[idx]   = y;
}

// one wave per edge: p_next[row][lane] += val * p[col][lane]
__global__ void spmm_kernel(const int*   __restrict__ rows,
                            const int*   __restrict__ cols,
                            const float* __restrict__ vals,
                            const float* __restrict__ p,
                            float*       __restrict__ pn) {
    int e    = blockIdx.x * 4 + (threadIdx.x >> 6);
    int lane = threadIdx.x & 63;
    if (e >= NNZ) return;
    int   r = rows[e];
    int   c = cols[e];
    float v = vals[e];
    float m = v * p[(size_t)c * D + lane];
    atomicAdd(&pn[(size_t)r * D + lane], m);
}

// p = lrelu_l2norm(p); acc += p
__global__ void norm_acc_kernel(float* __restrict__ pn,
                                float* __restrict__ acc) {
    int row  = blockIdx.x * 4 + (threadIdx.x >> 6);
    int lane = threadIdx.x & 63;
    if (row >= N_NODES) return;
    size_t idx = (size_t)row * D + lane;
    float x = pn[idx];
    x = (x >= 0.f) ? x : NEG_SLOPE * x;
    float norm = sqrtf(wave_sum64(x * x));
    float y = x / fmaxf(norm, EPS_NRM);
    pn[idx]   = y;
    acc[idx] += y;
}

// out[which*BATCH + b] = sigmoid( dot(merged[user], merged[NUM_USERS+item]) )
// merged = acc / 4  -> fold the 1/4 into each operand (1/16 on the product)
__global__ void score_kernel(const int* __restrict__ users,
                             const int* __restrict__ it0,
                             const int* __restrict__ it1,
                             const int* __restrict__ it2,
                             const float* __restrict__ acc,
                             float* __restrict__ out) {
    int task = blockIdx.x * 4 + (threadIdx.x >> 6);
    int lane = threadIdx.x & 63;
    if (task >= 3 * BATCH) return;
    int which = task >> 13;        // / BATCH (8192)
    int b     = task & (BATCH - 1);
    int u  = users[b];
    int it = (which == 0) ? it0[b] : (which == 1) ? it1[b] : it2[b];
    float uv = acc[(size_t)u * D + lane] * 0.25f;
    float iv = acc[(size_t)(NUM_USERS + it) * D + lane] * 0.25f;
    float s  = wave_sum64(uv * iv);
    if (lane == 0)
        out[which * BATCH + b] = 1.f / (1.f + expf(-s));
}

extern "C" void kernel_launch(void* const* d_in, const int* in_sizes, int n_in,
                              void* d_out, int out_size, void* d_ws, size_t ws_size,
                              hipStream_t stream) {
    const int*   users  = (const int*)  d_in[0];
    const int*   adj    = (const int*)  d_in[1];
    const int*   weak   = (const int*)  d_in[2];
    const int*   strong = (const int*)  d_in[3];
    const int*   erows  = (const int*)  d_in[4];
    const int*   ecols  = (const int*)  d_in[5];
    const float* evals  = (const float*)d_in[6];
    const float* upref  = (const float*)d_in[7];
    const float* ipref  = (const float*)d_in[8];
    float* out = (float*)d_out;

    const size_t rowElems = (size_t)N_NODES * D;
    float* acc = (float*)d_ws;
    float* pA  = acc + rowElems;
    float* pB  = pA  + rowElems;

    init_kernel<<<(N_NODES + 3) / 4, 256, 0, stream>>>(upref, ipref, acc, pA);

    float* pc = pA;
    float* pn = pB;
    for (int l = 0; l < 3; ++l) {
        hipMemsetAsync(pn, 0, rowElems * sizeof(float), stream);
        spmm_kernel<<<(NNZ + 3) / 4, 256, 0, stream>>>(erows, ecols, evals, pc, pn);
        norm_acc_kernel<<<(N_NODES + 3) / 4, 256, 0, stream>>>(pn, acc);
        float* t = pc; pc = pn; pn = t;
    }

    score_kernel<<<(3 * BATCH + 3) / 4, 256, 0, stream>>>(users, adj, weak, strong, acc, out);
}

// Round 2
// 1019.524 us; speedup vs baseline: 1.7443x; 1.7443x over previous
//
#include <hip/hip_runtime.h>
#include <math.h>

#define D 64
#define NUM_USERS 100000
#define NUM_ITEMS 50000
#define N_NODES 150000   // NUM_USERS + NUM_ITEMS
#define NNZ 2400000
#define BATCH 8192
#define NEG_SLOPE 0.1f
#define EPS_NRM 1e-12f

#define NB ((N_NODES + 255) / 256)   // 586 scan blocks (<=1024)

typedef unsigned short ushort_t;

__device__ __forceinline__ float wave_sum64(float v) {
    #pragma unroll
    for (int off = 32; off > 0; off >>= 1)
        v += __shfl_xor(v, off, 64);
    return v;
}

__device__ __forceinline__ float bf2f(ushort_t u) {
    return __uint_as_float(((unsigned)u) << 16);
}
__device__ __forceinline__ ushort_t f2bf(float f) {
    unsigned x = __float_as_uint(f);
    unsigned r = (x + 0x7FFFu + ((x >> 16) & 1u)) >> 16;   // RNE
    return (ushort_t)r;
}

// ---------- CSR build ----------
__global__ void hist_kernel(const int* __restrict__ rows, int* __restrict__ cnt) {
    int e = blockIdx.x * 256 + threadIdx.x;
    if (e < NNZ) atomicAdd(&cnt[rows[e]], 1);
}

// per-block exclusive scan (256 elems/block); bsums[b] = block total
__global__ void scan1_kernel(const int* __restrict__ in, int* __restrict__ out,
                             int* __restrict__ bsums) {
    int tid = threadIdx.x, gid = blockIdx.x * 256 + tid;
    int v = (gid < N_NODES) ? in[gid] : 0;
    int lane = tid & 63, w = tid >> 6;
    int s = v;
    #pragma unroll
    for (int off = 1; off < 64; off <<= 1) {
        int t = __shfl_up(s, off, 64);
        if (lane >= off) s += t;
    }
    __shared__ int wsum[4];
    if (lane == 63) wsum[w] = s;
    __syncthreads();
    if (tid == 0) {
        int a = 0;
        #pragma unroll
        for (int i = 0; i < 4; i++) { int t = wsum[i]; wsum[i] = a; a += t; }
    }
    __syncthreads();
    int incl = s + wsum[w];
    if (gid < N_NODES) out[gid] = incl - v;     // exclusive
    if (tid == 255) bsums[blockIdx.x] = incl;   // block total
}

// single-block exclusive scan of block sums (n <= 1024)
__global__ void scan2_kernel(int* __restrict__ bsums, int n) {
    int tid = threadIdx.x;
    int v = (tid < n) ? bsums[tid] : 0;
    int lane = tid & 63, w = tid >> 6;
    int s = v;
    #pragma unroll
    for (int off = 1; off < 64; off <<= 1) {
        int t = __shfl_up(s, off, 64);
        if (lane >= off) s += t;
    }
    __shared__ int wsum[16];
    if (lane == 63) wsum[w] = s;
    __syncthreads();
    if (tid == 0) {
        int a = 0;
        #pragma unroll
        for (int i = 0; i < 16; i++) { int t = wsum[i]; wsum[i] = a; a += t; }
    }
    __syncthreads();
    int incl = s + wsum[w];
    if (tid < n) bsums[tid] = incl - v;
}

__global__ void scan3_kernel(int* __restrict__ rowptr, const int* __restrict__ bsums,
                             int* __restrict__ cursor) {
    int gid = blockIdx.x * 256 + threadIdx.x;
    if (gid < N_NODES) {
        int v = rowptr[gid] + bsums[blockIdx.x];
        rowptr[gid] = v;
        cursor[gid] = v;
    }
    if (gid == 0) rowptr[N_NODES] = NNZ;
}

__global__ void scatter_kernel(const int* __restrict__ rows, const int* __restrict__ cols,
                               const float* __restrict__ vals, int* __restrict__ cursor,
                               int2* __restrict__ es) {
    int e = blockIdx.x * 256 + threadIdx.x;
    if (e < NNZ) {
        int r = rows[e];
        int pos = atomicAdd(&cursor[r], 1);
        es[pos] = make_int2(cols[e], __float_as_int(vals[e]));
    }
}

// ---------- GCN ----------
__global__ void init_kernel(const float* __restrict__ upref,
                            const float* __restrict__ ipref,
                            float* __restrict__ acc,
                            ushort_t* __restrict__ p) {
    int row  = blockIdx.x * 4 + (threadIdx.x >> 6);
    int lane = threadIdx.x & 63;
    if (row >= N_NODES) return;
    float x = (row < NUM_USERS) ? upref[(size_t)row * D + lane]
                                : ipref[(size_t)(row - NUM_USERS) * D + lane];
    x = (x >= 0.f) ? x : NEG_SLOPE * x;
    float norm = sqrtf(wave_sum64(x * x));
    float y = x / fmaxf(norm, EPS_NRM);
    size_t idx = (size_t)row * D + lane;
    acc[idx] = y;
    p[idx]   = f2bf(y);
}

// one wave per row: gather + fused lrelu/l2norm + acc update (no atomics)
__global__ void gather_kernel(const int* __restrict__ rowptr,
                              const int2* __restrict__ es,
                              const ushort_t* __restrict__ p,
                              ushort_t* __restrict__ pn,
                              float* __restrict__ acc) {
    int row  = blockIdx.x * 4 + (threadIdx.x >> 6);
    int lane = threadIdx.x & 63;
    if (row >= N_NODES) return;
    int beg = rowptr[row], end = rowptr[row + 1];
    float a = 0.f;
    for (int e = beg; e < end; e++) {
        int2 cv = es[e];
        a += __int_as_float(cv.y) * bf2f(p[(size_t)cv.x * D + lane]);
    }
    float x = (a >= 0.f) ? a : NEG_SLOPE * a;
    float norm = sqrtf(wave_sum64(x * x));
    float y = x / fmaxf(norm, EPS_NRM);
    size_t idx = (size_t)row * D + lane;
    pn[idx]   = f2bf(y);
    acc[idx] += y;
}

__global__ void score_kernel(const int* __restrict__ users,
                             const int* __restrict__ it0,
                             const int* __restrict__ it1,
                             const int* __restrict__ it2,
                             const float* __restrict__ acc,
                             float* __restrict__ out) {
    int task = blockIdx.x * 4 + (threadIdx.x >> 6);
    int lane = threadIdx.x & 63;
    if (task >= 3 * BATCH) return;
    int which = task >> 13;
    int b     = task & (BATCH - 1);
    int u  = users[b];
    int it = (which == 0) ? it0[b] : (which == 1) ? it1[b] : it2[b];
    float uv = acc[(size_t)u * D + lane] * 0.25f;
    float iv = acc[(size_t)(NUM_USERS + it) * D + lane] * 0.25f;
    float s  = wave_sum64(uv * iv);
    if (lane == 0)
        out[which * BATCH + b] = 1.f / (1.f + expf(-s));
}

extern "C" void kernel_launch(void* const* d_in, const int* in_sizes, int n_in,
                              void* d_out, int out_size, void* d_ws, size_t ws_size,
                              hipStream_t stream) {
    const int*   users  = (const int*)  d_in[0];
    const int*   adj    = (const int*)  d_in[1];
    const int*   weak   = (const int*)  d_in[2];
    const int*   strong = (const int*)  d_in[3];
    const int*   erows  = (const int*)  d_in[4];
    const int*   ecols  = (const int*)  d_in[5];
    const float* evals  = (const float*)d_in[6];
    const float* upref  = (const float*)d_in[7];
    const float* ipref  = (const float*)d_in[8];
    float* out = (float*)d_out;

    const size_t rowElems = (size_t)N_NODES * D;   // 9.6M

    char* base = (char*)d_ws;
    size_t off = 0;
    auto alloc = [&](size_t bytes) {
        char* p = base + off;
        off = (off + bytes + 255) & ~(size_t)255;
        return (void*)p;
    };
    float*    acc    = (float*)   alloc(rowElems * sizeof(float));    // 38.4 MB
    ushort_t* pA     = (ushort_t*)alloc(rowElems * sizeof(ushort_t)); // 19.2 MB
    ushort_t* pB     = (ushort_t*)alloc(rowElems * sizeof(ushort_t)); // 19.2 MB
    int2*     es     = (int2*)    alloc((size_t)NNZ * sizeof(int2));  // 19.2 MB
    int*      rowptr = (int*)     alloc((N_NODES + 1) * sizeof(int));
    int*      cursor = (int*)     alloc(N_NODES * sizeof(int));
    int*      rcnt   = (int*)     alloc(N_NODES * sizeof(int));
    int*      bsums  = (int*)     alloc(1024 * sizeof(int));

    // ---- build CSR (once per launch) ----
    hipMemsetAsync(rcnt, 0, N_NODES * sizeof(int), stream);
    hist_kernel<<<(NNZ + 255) / 256, 256, 0, stream>>>(erows, rcnt);
    scan1_kernel<<<NB, 256, 0, stream>>>(rcnt, rowptr, bsums);
    scan2_kernel<<<1, 1024, 0, stream>>>(bsums, NB);
    scan3_kernel<<<NB, 256, 0, stream>>>(rowptr, bsums, cursor);
    scatter_kernel<<<(NNZ + 255) / 256, 256, 0, stream>>>(erows, ecols, evals, cursor, es);

    // ---- GCN layers ----
    init_kernel<<<(N_NODES + 3) / 4, 256, 0, stream>>>(upref, ipref, acc, pA);

    ushort_t* pc = pA;
    ushort_t* pn = pB;
    for (int l = 0; l < 3; ++l) {
        gather_kernel<<<(N_NODES + 3) / 4, 256, 0, stream>>>(rowptr, es, pc, pn, acc);
        ushort_t* t = pc; pc = pn; pn = t;
    }

    score_kernel<<<(3 * BATCH + 3) / 4, 256, 0, stream>>>(users, adj, weak, strong, acc, out);
}

// Round 3
// 689.429 us; speedup vs baseline: 2.5794x; 1.4788x over previous
//
#include <hip/hip_runtime.h>
#include <math.h>

#define D 64
#define NUM_USERS 100000
#define NUM_ITEMS 50000
#define N_NODES 150000   // NUM_USERS + NUM_ITEMS
#define NNZ 2400000
#define BATCH 8192
#define NEG_SLOPE 0.1f
#define EPS_NRM 1e-12f

#define NB ((N_NODES + 255) / 256)   // 586 scan blocks (<=1024)

typedef unsigned short ushort_t;

__device__ __forceinline__ float wave_sum64(float v) {
    #pragma unroll
    for (int off = 32; off > 0; off >>= 1)
        v += __shfl_xor(v, off, 64);
    return v;
}

__device__ __forceinline__ ushort_t f2bf(float f) {
    unsigned x = __float_as_uint(f);
    unsigned r = (x + 0x7FFFu + ((x >> 16) & 1u)) >> 16;   // RNE
    return (ushort_t)r;
}

// ---------- CSR build ----------
__global__ void hist_kernel(const int* __restrict__ rows, int* __restrict__ cnt) {
    int e = blockIdx.x * 256 + threadIdx.x;
    if (e < NNZ) atomicAdd(&cnt[rows[e]], 1);
}

__global__ void scan1_kernel(const int* __restrict__ in, int* __restrict__ out,
                             int* __restrict__ bsums) {
    int tid = threadIdx.x, gid = blockIdx.x * 256 + tid;
    int v = (gid < N_NODES) ? in[gid] : 0;
    int lane = tid & 63, w = tid >> 6;
    int s = v;
    #pragma unroll
    for (int off = 1; off < 64; off <<= 1) {
        int t = __shfl_up(s, off, 64);
        if (lane >= off) s += t;
    }
    __shared__ int wsum[4];
    if (lane == 63) wsum[w] = s;
    __syncthreads();
    if (tid == 0) {
        int a = 0;
        #pragma unroll
        for (int i = 0; i < 4; i++) { int t = wsum[i]; wsum[i] = a; a += t; }
    }
    __syncthreads();
    int incl = s + wsum[w];
    if (gid < N_NODES) out[gid] = incl - v;     // exclusive
    if (tid == 255) bsums[blockIdx.x] = incl;   // block total
}

__global__ void scan2_kernel(int* __restrict__ bsums, int n) {
    int tid = threadIdx.x;
    int v = (tid < n) ? bsums[tid] : 0;
    int lane = tid & 63, w = tid >> 6;
    int s = v;
    #pragma unroll
    for (int off = 1; off < 64; off <<= 1) {
        int t = __shfl_up(s, off, 64);
        if (lane >= off) s += t;
    }
    __shared__ int wsum[16];
    if (lane == 63) wsum[w] = s;
    __syncthreads();
    if (tid == 0) {
        int a = 0;
        #pragma unroll
        for (int i = 0; i < 16; i++) { int t = wsum[i]; wsum[i] = a; a += t; }
    }
    __syncthreads();
    int incl = s + wsum[w];
    if (tid < n) bsums[tid] = incl - v;
}

__global__ void scan3_kernel(int* __restrict__ rowptr, const int* __restrict__ bsums,
                             int* __restrict__ cursor) {
    int gid = blockIdx.x * 256 + threadIdx.x;
    if (gid < N_NODES) {
        int v = rowptr[gid] + bsums[blockIdx.x];
        rowptr[gid] = v;
        cursor[gid] = v;
    }
    if (gid == 0) rowptr[N_NODES] = NNZ;
}

__global__ void scatter_kernel(const int* __restrict__ rows, const int* __restrict__ cols,
                               const float* __restrict__ vals, int* __restrict__ cursor,
                               int2* __restrict__ es) {
    int e = blockIdx.x * 256 + threadIdx.x;
    if (e < NNZ) {
        int r = rows[e];
        int pos = atomicAdd(&cursor[r], 1);
        es[pos] = make_int2(cols[e], __float_as_int(vals[e]));
    }
}

// ---------- GCN ----------
__global__ void init_kernel(const float* __restrict__ upref,
                            const float* __restrict__ ipref,
                            float* __restrict__ acc,
                            ushort_t* __restrict__ p) {
    int row  = blockIdx.x * 4 + (threadIdx.x >> 6);
    int lane = threadIdx.x & 63;
    if (row >= N_NODES) return;
    float x = (row < NUM_USERS) ? upref[(size_t)row * D + lane]
                                : ipref[(size_t)(row - NUM_USERS) * D + lane];
    x = (x >= 0.f) ? x : NEG_SLOPE * x;
    float norm = sqrtf(wave_sum64(x * x));
    float y = x / fmaxf(norm, EPS_NRM);
    size_t idx = (size_t)row * D + lane;
    acc[idx] = y;
    p[idx]   = f2bf(y);
}

// one wave per row; 4 edges in flight (sub = lane>>4), 4 features/lane (fl = lane&15)
__global__ void gather_kernel(const int* __restrict__ rowptr,
                              const int2* __restrict__ es,
                              const ushort_t* __restrict__ p,
                              ushort_t* __restrict__ pn,
                              float* __restrict__ acc) {
    int row  = blockIdx.x * 4 + (threadIdx.x >> 6);
    int lane = threadIdx.x & 63;
    if (row >= N_NODES) return;
    int sub = lane >> 4;
    int fl  = lane & 15;
    int beg = rowptr[row], end = rowptr[row + 1];

    float a0 = 0.f, a1 = 0.f, a2 = 0.f, a3 = 0.f;
    for (int e = beg + sub; e < end; e += 4) {
        int2 cv = es[e];
        float v = __int_as_float(cv.y);
        const uint2 q = *(const uint2*)(p + (size_t)cv.x * D + fl * 4);
        float f0 = __uint_as_float(q.x << 16);
        float f1 = __uint_as_float(q.x & 0xFFFF0000u);
        float f2 = __uint_as_float(q.y << 16);
        float f3 = __uint_as_float(q.y & 0xFFFF0000u);
        a0 = fmaf(v, f0, a0);
        a1 = fmaf(v, f1, a1);
        a2 = fmaf(v, f2, a2);
        a3 = fmaf(v, f3, a3);
    }
    // reduce across the 4 sub-groups (lanes fl, fl+16, fl+32, fl+48)
    a0 += __shfl_xor(a0, 16, 64); a0 += __shfl_xor(a0, 32, 64);
    a1 += __shfl_xor(a1, 16, 64); a1 += __shfl_xor(a1, 32, 64);
    a2 += __shfl_xor(a2, 16, 64); a2 += __shfl_xor(a2, 32, 64);
    a3 += __shfl_xor(a3, 16, 64); a3 += __shfl_xor(a3, 32, 64);

    float x0 = (a0 >= 0.f) ? a0 : NEG_SLOPE * a0;
    float x1 = (a1 >= 0.f) ? a1 : NEG_SLOPE * a1;
    float x2 = (a2 >= 0.f) ? a2 : NEG_SLOPE * a2;
    float x3 = (a3 >= 0.f) ? a3 : NEG_SLOPE * a3;

    float ss = x0 * x0 + x1 * x1 + x2 * x2 + x3 * x3;
    ss += __shfl_xor(ss, 1, 64);
    ss += __shfl_xor(ss, 2, 64);
    ss += __shfl_xor(ss, 4, 64);
    ss += __shfl_xor(ss, 8, 64);
    float inv = 1.f / fmaxf(sqrtf(ss), EPS_NRM);
    float y0 = x0 * inv, y1 = x1 * inv, y2 = x2 * inv, y3 = x3 * inv;

    if (sub == 0) {
        uint2 o;
        o.x = (unsigned)f2bf(y0) | ((unsigned)f2bf(y1) << 16);
        o.y = (unsigned)f2bf(y2) | ((unsigned)f2bf(y3) << 16);
        *(uint2*)(pn + (size_t)row * D + fl * 4) = o;
    } else if (sub == 1) {
        float4* ap = (float4*)(acc + (size_t)row * D + fl * 4);
        float4 av = *ap;
        av.x += y0; av.y += y1; av.z += y2; av.w += y3;
        *ap = av;
    }
}

__global__ void score_kernel(const int* __restrict__ users,
                             const int* __restrict__ it0,
                             const int* __restrict__ it1,
                             const int* __restrict__ it2,
                             const float* __restrict__ acc,
                             float* __restrict__ out) {
    int task = blockIdx.x * 4 + (threadIdx.x >> 6);
    int lane = threadIdx.x & 63;
    if (task >= 3 * BATCH) return;
    int which = task >> 13;
    int b     = task & (BATCH - 1);
    int u  = users[b];
    int it = (which == 0) ? it0[b] : (which == 1) ? it1[b] : it2[b];
    float uv = acc[(size_t)u * D + lane] * 0.25f;
    float iv = acc[(size_t)(NUM_USERS + it) * D + lane] * 0.25f;
    float s  = wave_sum64(uv * iv);
    if (lane == 0)
        out[which * BATCH + b] = 1.f / (1.f + expf(-s));
}

extern "C" void kernel_launch(void* const* d_in, const int* in_sizes, int n_in,
                              void* d_out, int out_size, void* d_ws, size_t ws_size,
                              hipStream_t stream) {
    const int*   users  = (const int*)  d_in[0];
    const int*   adj    = (const int*)  d_in[1];
    const int*   weak   = (const int*)  d_in[2];
    const int*   strong = (const int*)  d_in[3];
    const int*   erows  = (const int*)  d_in[4];
    const int*   ecols  = (const int*)  d_in[5];
    const float* evals  = (const float*)d_in[6];
    const float* upref  = (const float*)d_in[7];
    const float* ipref  = (const float*)d_in[8];
    float* out = (float*)d_out;

    const size_t rowElems = (size_t)N_NODES * D;   // 9.6M

    char* base = (char*)d_ws;
    size_t off = 0;
    auto alloc = [&](size_t bytes) {
        char* p = base + off;
        off = (off + bytes + 255) & ~(size_t)255;
        return (void*)p;
    };
    float*    acc    = (float*)   alloc(rowElems * sizeof(float));    // 38.4 MB
    ushort_t* pA     = (ushort_t*)alloc(rowElems * sizeof(ushort_t)); // 19.2 MB
    ushort_t* pB     = (ushort_t*)alloc(rowElems * sizeof(ushort_t)); // 19.2 MB
    int2*     es     = (int2*)    alloc((size_t)NNZ * sizeof(int2));  // 19.2 MB
    int*      rowptr = (int*)     alloc((N_NODES + 1) * sizeof(int));
    int*      cursor = (int*)     alloc(N_NODES * sizeof(int));
    int*      rcnt   = (int*)     alloc(N_NODES * sizeof(int));
    int*      bsums  = (int*)     alloc(1024 * sizeof(int));

    // ---- build CSR (once per launch) ----
    hipMemsetAsync(rcnt, 0, N_NODES * sizeof(int), stream);
    hist_kernel<<<(NNZ + 255) / 256, 256, 0, stream>>>(erows, rcnt);
    scan1_kernel<<<NB, 256, 0, stream>>>(rcnt, rowptr, bsums);
    scan2_kernel<<<1, 1024, 0, stream>>>(bsums, NB);
    scan3_kernel<<<NB, 256, 0, stream>>>(rowptr, bsums, cursor);
    scatter_kernel<<<(NNZ + 255) / 256, 256, 0, stream>>>(erows, ecols, evals, cursor, es);

    // ---- GCN layers ----
    init_kernel<<<(N_NODES + 3) / 4, 256, 0, stream>>>(upref, ipref, acc, pA);

    ushort_t* pc = pA;
    ushort_t* pn = pB;
    for (int l = 0; l < 3; ++l) {
        gather_kernel<<<(N_NODES + 3) / 4, 256, 0, stream>>>(rowptr, es, pc, pn, acc);
        ushort_t* t = pc; pc = pn; pn = t;
    }

    score_kernel<<<(3 * BATCH + 3) / 4, 256, 0, stream>>>(users, adj, weak, strong, acc, out);
}